// Round 7
// baseline (1865.353 us; speedup 1.0000x reference)
//
#include <hip/hip_runtime.h>
#include <cstdint>
#include <cstddef>

#define Bsz 2048
#define Tseq 60
#define Fin 89
#define Hd 1024
#define G4 4096
#define KXP 128   // x/W K padded to 2x BK=64 so all rounds are uniform
#define NOUT 30

typedef _Float16 half8 __attribute__((ext_vector_type(8)));
typedef float f32x4 __attribute__((ext_vector_type(4)));

__device__ __forceinline__ void gload_lds16(const void* g, void* l) {
  __builtin_amdgcn_global_load_lds((const __attribute__((address_space(1))) void*)g,
                                   (__attribute__((address_space(3))) void*)l,
                                   16, 0, 0);
}

__device__ __forceinline__ float sigmoidf_fast(float x) {
  return 1.0f / (1.0f + __expf(-x));
}

// ---------------------------------------------------------------------------
// Prep kernels (run once per launch; ws is re-poisoned before every call)
// ---------------------------------------------------------------------------

// x [B][T][Fin] fp32 -> xp [T][B][KXP] fp16, zero-padded k in [Fin, KXP)
__global__ __launch_bounds__(256) void convert_x(const float* __restrict__ x,
                                                 _Float16* __restrict__ xp) {
  int idx = blockIdx.x * 256 + threadIdx.x;   // < Tseq*Bsz*KXP
  int k = idx % KXP;
  int b = (idx / KXP) % Bsz;
  int t = idx / (KXP * Bsz);
  float v = (k < Fin) ? x[((size_t)b * Tseq + t) * Fin + k] : 0.0f;
  xp[idx] = (_Float16)v;
}

// W [Fin][G4] fp32 -> Wpt [G4][KXP] fp16 (B^T layout, zero rows k>=Fin)
__global__ __launch_bounds__(256) void transpose_W(const float* __restrict__ W,
                                                   _Float16* __restrict__ Wpt) {
  __shared__ float tile[32][33];
  int n0 = blockIdx.x * 32;
  int k0 = blockIdx.y * 32;
  int tx = threadIdx.x, ty = threadIdx.y;
  for (int i = ty; i < 32; i += 8) {
    int k = k0 + i;
    tile[i][tx] = (k < Fin) ? W[(size_t)k * G4 + n0 + tx] : 0.0f;
  }
  __syncthreads();
  for (int i = ty; i < 32; i += 8)
    Wpt[(size_t)(n0 + i) * KXP + k0 + tx] = (_Float16)tile[tx][i];
}

// U [Hd][G4] fp32 -> Upt [G4][Hd] fp16 (B^T layout)
__global__ __launch_bounds__(256) void transpose_U(const float* __restrict__ U,
                                                   _Float16* __restrict__ Upt) {
  __shared__ float tile[32][33];
  int n0 = blockIdx.x * 32;
  int k0 = blockIdx.y * 32;
  int tx = threadIdx.x, ty = threadIdx.y;
  for (int i = ty; i < 32; i += 8)
    tile[i][tx] = U[(size_t)(k0 + i) * G4 + n0 + tx];
  __syncthreads();
  for (int i = ty; i < 32; i += 8)
    Upt[(size_t)(n0 + i) * Hd + k0 + tx] = (_Float16)tile[tx][i];
}

// ---------------------------------------------------------------------------
// One LSTM step (60 launches -- persistent-kernel design abandoned after the
// round-6 replay race + 2.7x slowdown).
//
// NEW structure (rounds 0-5 showed EVERY schedule of the 128x128/2-deep/
// 64KB shape lands at the serial SUM of DMA+LDS+MFMA ~28.5us/step):
//   - Tile 128m x 256n (4 gates x 64 hidden units), 8 waves / 512 threads,
//     ONE block per CU. B-DMA redundancy halves (16x -> 8x); per-XCD
//     working set (A 2.35MB + B 2.36MB) ~L2-resident with the swizzle below.
//   - 3-deep LDS pipeline (3 bufs x 48KB = 144KB of the 160KB/CU): DMA for
//     rounds r+1, r+2 in flight while computing r -> the counted
//     `s_waitcnt vmcnt(12)` is satisfied on arrival and DMA leaves the
//     critical path entirely (2-deep gave it only ~1 round of slack).
//   - Per-wave microkernel unchanged from the proven 128x128 kernel
//     (4mi x 4p, two 32-k subtiles, asm ds_read_b128, split lgkmcnt(8)/(0),
//     m89 epilogue); only the unit-index formulas changed.
//   - Wave w: m-half (w>>2) (rows 64*(w>>2)..+63), j-quarter (w&3)
//     (hidden units j0+16*(w&3)..+15), all 4 gates.
//
// LDS layout per 16-row x 32-half unit (1KB), XOR-chunk swizzled exactly as
// before (slot s of row r holds global chunk s^((r>>1)&3); read slot
// quad^((l16>>1)&3)): conflict-free, global_load_lds-compatible.
//
// XCD swizzle (256 blocks, 8 XCDs round-robin): XCD x owns j-panels
// 4*(x&3)..+3 and m-panels 8*(x>>2)..+7 (bijective; 32 blocks/XCD).
// ---------------------------------------------------------------------------
__global__ __launch_bounds__(512, 1) void lstm_step(
    const _Float16* __restrict__ xp_t,  // [Bsz][KXP]  (this timestep)
    const _Float16* __restrict__ Wpt,   // [G4][KXP]   (B^T)
    const _Float16* __restrict__ Upt,   // [G4][Hd]    (B^T)
    const float*    __restrict__ bias,  // [G4]
    const _Float16* __restrict__ h_in,  // [Bsz][Hd]
    _Float16*       __restrict__ h_out, // [Bsz][Hd]
    float*          __restrict__ cst,   // [Bsz][Hd]
    int skip_h)                          // t==0: only x@W, c_prev = 0
{
  __shared__ __align__(16) _Float16 As[3 * 8192];   // 3 bufs x (2 st x 8 units)  = 48KB
  __shared__ __align__(16) _Float16 Bs[3 * 16384];  // 3 bufs x (2 st x 16 units) = 96KB

  const int tid  = threadIdx.x;
  const int wave = tid >> 6;          // 0..7
  const int lane = tid & 63;
  const int quad = lane >> 4;
  const int l16  = lane & 15;

  // XCD swizzle: id -> (m-panel, j-panel), 16 x 16 grid, bijective.
  const int id  = blockIdx.x;
  const int xcd = id & 7, loc = id >> 3;              // loc in [0,32)
  const int jpanel = 4 * (xcd & 3) + (loc & 3);       // 0..15
  const int mpanel = 8 * (xcd >> 2) + (loc >> 2);     // 0..15
  const int m0 = mpanel * 128;    // batch-row base
  const int j0 = jpanel * 64;     // hidden-unit base (64 units x 4 gates = 256 N)

  const int srow = lane >> 2;                      // staging row in unit
  const int qg   = (lane & 3) ^ ((lane >> 3) & 3); // staging global chunk
  const int sA   = quad ^ ((l16 >> 1) & 3);        // fragment LDS slot

  const int mhalf = wave >> 2;        // 0..1
  const int nq    = wave & 3;         // 0..3
  const int j  = j0 + 16 * nq + l16;  // this lane's hidden unit
  const int aoff = l16 * 32 + sA * 8; // fragment offset within unit (halfs)

  float bv[4];
#pragma unroll
  for (int p = 0; p < 4; ++p) bv[p] = bias[p * Hd + j];

  f32x4 acc[4][4];
#pragma unroll
  for (int mi = 0; mi < 4; ++mi)
#pragma unroll
    for (int p = 0; p < 4; ++p)
      acc[mi][p] = f32x4{bv[p], bv[p], bv[p], bv[p]};

  // stage one round's 48 KB (A 16KB + B 32KB) into buffer `buf` (async DMA).
  // Exactly 6 global_load_lds per WAVE (2 A + 4 B) -> vmcnt granularity = 6.
  auto stage = [&](int buf, int r) {
    const _Float16* Ab; const _Float16* Bb; int strA, strB, k0;
    if (r < 2) { Ab = xp_t; strA = KXP; Bb = Wpt; strB = KXP; k0 = r * 64; }
    else       { Ab = h_in; strA = Hd;  Bb = Upt; strB = Hd;  k0 = (r - 2) * 64; }
    _Float16* Ad = &As[buf * 8192];
    _Float16* Bd = &Bs[buf * 16384];
#pragma unroll
    for (int ii = 0; ii < 2; ++ii) {           // A: 16 unit-chunks
      int i = ii * 8 + wave;                   // 0..15
      int st = i >> 3, ci = i & 7;
      gload_lds16(Ab + (size_t)(m0 + ci * 16 + srow) * strA + k0 + st * 32 + qg * 8,
                  Ad + st * 4096 + ci * 512);
    }
#pragma unroll
    for (int ii = 0; ii < 4; ++ii) {           // B: 32 unit-chunks
      int i = ii * 8 + wave;                   // 0..31
      int st = i >> 4, ci = i & 15;            // ci: gate (ci>>2), j-group (ci&3)
      int gn = (ci >> 2) * Hd + j0 + 16 * (ci & 3) + srow;
      gload_lds16(Bb + (size_t)gn * strB + k0 + st * 32 + qg * 8,
                  Bd + st * 8192 + ci * 512);
    }
  };

  // consume buffer `buf`: 16 asm ds_read_b128 (compiler-opaque) + 32 MFMA,
  // split per k-subtile so st1-read latency hides under st0 MFMAs.
  auto compute = [&](int buf) {
    const __attribute__((address_space(3))) _Float16* As3 =
        (const __attribute__((address_space(3))) _Float16*)&As[buf * 8192];
    const __attribute__((address_space(3))) _Float16* Bs3 =
        (const __attribute__((address_space(3))) _Float16*)&Bs[buf * 16384];
    half8 a0[4], b0[4], a1[4], b1[4];
#pragma unroll
    for (int mi = 0; mi < 4; ++mi)
      asm volatile("ds_read_b128 %0, %1" : "=v"(a0[mi])
                   : "v"(As3 + (4 * mhalf + mi) * 512 + aoff) : "memory");
#pragma unroll
    for (int p = 0; p < 4; ++p)
      asm volatile("ds_read_b128 %0, %1" : "=v"(b0[p])
                   : "v"(Bs3 + (4 * p + nq) * 512 + aoff) : "memory");
#pragma unroll
    for (int mi = 0; mi < 4; ++mi)
      asm volatile("ds_read_b128 %0, %1" : "=v"(a1[mi])
                   : "v"(As3 + 4096 + (4 * mhalf + mi) * 512 + aoff) : "memory");
#pragma unroll
    for (int p = 0; p < 4; ++p)
      asm volatile("ds_read_b128 %0, %1" : "=v"(b1[p])
                   : "v"(Bs3 + 8192 + (4 * p + nq) * 512 + aoff) : "memory");
    asm volatile("s_waitcnt lgkmcnt(8)" ::: "memory");
    __builtin_amdgcn_sched_barrier(0);   // rule #18: pin MFMAs below the wait
#pragma unroll
    for (int mi = 0; mi < 4; ++mi)
#pragma unroll
      for (int p = 0; p < 4; ++p)
        acc[mi][p] = __builtin_amdgcn_mfma_f32_16x16x32_f16(a0[mi], b0[p],
                                                            acc[mi][p], 0, 0, 0);
    asm volatile("s_waitcnt lgkmcnt(0)" ::: "memory");
    __builtin_amdgcn_sched_barrier(0);
#pragma unroll
    for (int mi = 0; mi < 4; ++mi)
#pragma unroll
      for (int p = 0; p < 4; ++p)
        acc[mi][p] = __builtin_amdgcn_mfma_f32_16x16x32_f16(a1[mi], b1[p],
                                                            acc[mi][p], 0, 0, 0);
  };

  const int NR = skip_h ? 2 : 18;

  // Prologue: fill the 3-deep pipeline (rounds 0..2).
  stage(0, 0);
  stage(1, 1);
  if (NR > 2) stage(2, 2);

  for (int r = 0; r < NR; ++r) {
    const int cur = r % 3;
    // wait for round r's 6 loads; keep up to 2 future rounds (12) in flight.
    if (NR - r >= 3)      asm volatile("s_waitcnt vmcnt(12)" ::: "memory");
    else if (NR - r == 2) asm volatile("s_waitcnt vmcnt(6)"  ::: "memory");
    else                  asm volatile("s_waitcnt vmcnt(0)"  ::: "memory");
    __builtin_amdgcn_sched_barrier(0);
    __builtin_amdgcn_s_barrier();       // all waves: buf `cur` landed
    __builtin_amdgcn_s_setprio(1);
    compute(cur);                       // ends with lgkmcnt(0): reads consumed
    __builtin_amdgcn_s_setprio(0);
    __builtin_amdgcn_s_barrier();       // all waves done reading buf `cur`
    if (r + 3 < NR) stage(cur, r + 3);  // refill freed buffer (2 rounds ahead)
  }

  // epilogue: lane holds i,f,g,o for hidden unit j, rows quad*4+rr (m89 layout)
#pragma unroll
  for (int mi = 0; mi < 4; ++mi) {
#pragma unroll
    for (int rr = 0; rr < 4; ++rr) {
      int row = m0 + 64 * mhalf + mi * 16 + quad * 4 + rr;
      size_t idx = (size_t)row * Hd + j;
      float iv = sigmoidf_fast(acc[mi][0][rr]);
      float fv = sigmoidf_fast(acc[mi][1][rr]);
      float gv = fmaxf(acc[mi][2][rr], 0.0f);   // relu candidate
      float ov = sigmoidf_fast(acc[mi][3][rr]);
      float cprev = skip_h ? 0.0f : cst[idx];   // c_0 = 0 folded in
      float cv = fv * cprev + iv * gv;
      cst[idx] = cv;
      float hv = ov * fmaxf(cv, 0.0f);          // relu on cell output
      h_out[idx] = (_Float16)hv;
    }
  }
}

// ---------------------------------------------------------------------------
// y[b][o] = bd[o] + sum_k h[b][k] * Wd[k][o]
// ---------------------------------------------------------------------------
__global__ __launch_bounds__(256) void final_dense(const _Float16* __restrict__ h,
                                                   const float* __restrict__ Wd,
                                                   const float* __restrict__ bd,
                                                   float* __restrict__ y) {
  __shared__ float hs[Hd];
  __shared__ float red[8][32];
  int bi = blockIdx.x;
  for (int k = threadIdx.x; k < Hd; k += 256)
    hs[k] = (float)h[(size_t)bi * Hd + k];
  __syncthreads();
  int o  = threadIdx.x & 31;
  int ch = threadIdx.x >> 5;
  float p = 0.0f;
  if (o < NOUT) {
    int k0 = ch * (Hd / 8);
    for (int k = k0; k < k0 + (Hd / 8); ++k)
      p += hs[k] * Wd[(size_t)k * NOUT + o];
  }
  red[ch][o] = p;
  __syncthreads();
  if (threadIdx.x < NOUT) {
    float s = bd[threadIdx.x];
    for (int c2 = 0; c2 < 8; ++c2) s += red[c2][threadIdx.x];
    y[(size_t)bi * NOUT + threadIdx.x] = s;
  }
}

// ---------------------------------------------------------------------------

extern "C" void kernel_launch(void* const* d_in, const int* in_sizes, int n_in,
                              void* d_out, int out_size, void* d_ws, size_t ws_size,
                              hipStream_t stream) {
  const float* x  = (const float*)d_in[0];
  const float* W  = (const float*)d_in[1];
  const float* U  = (const float*)d_in[2];
  const float* b  = (const float*)d_in[3];
  const float* Wd = (const float*)d_in[4];
  const float* bd = (const float*)d_in[5];
  float* y = (float*)d_out;

  char* ws = (char*)d_ws;
  _Float16* xp  = (_Float16*)ws; ws += (size_t)Tseq * Bsz * KXP * 2;  // 31.5 MB
  _Float16* Wpt = (_Float16*)ws; ws += (size_t)G4 * KXP * 2;          // 1.05 MB
  _Float16* Upt = (_Float16*)ws; ws += (size_t)G4 * Hd * 2;           // 8.4 MB
  _Float16* hb0 = (_Float16*)ws; ws += (size_t)Bsz * Hd * 2;          // 4.2 MB
  _Float16* hb1 = (_Float16*)ws; ws += (size_t)Bsz * Hd * 2;          // 4.2 MB
  float*    cst = (float*)ws;    ws += (size_t)Bsz * Hd * 4;          // 8.4 MB

  convert_x<<<(Tseq * Bsz * KXP) / 256, 256, 0, stream>>>(x, xp);
  transpose_W<<<dim3(G4 / 32, KXP / 32), dim3(32, 8), 0, stream>>>(W, Wpt);
  transpose_U<<<dim3(G4 / 32, Hd / 32), dim3(32, 8), 0, stream>>>(U, Upt);

  for (int t = 0; t < Tseq; ++t) {
    const _Float16* hin  = ((t - 1) & 1) ? hb1 : hb0;   // unused at t=0
    _Float16*       hout = (t & 1) ? hb1 : hb0;
    lstm_step<<<dim3((Bsz / 128) * (G4 / 256)), 512, 0, stream>>>(
        xp + (size_t)t * (Bsz * KXP), Wpt, Upt, b,
        (t == 0) ? hb0 : hin, hout, cst, (t == 0) ? 1 : 0);
  }

  // h_{59} is in hb1 (59 & 1 == 1)
  final_dense<<<Bsz, 256, 0, stream>>>(hb1, Wd, bd, y);
}

// Round 10
// 1788.023 us; speedup vs baseline: 1.0432x; 1.0432x over previous
//
#include <hip/hip_runtime.h>
#include <cstdint>
#include <cstddef>

#define Bsz 2048
#define Tseq 60
#define Fin 89
#define Hd 1024
#define G4 4096
#define KXP 128   // x/W K padded to 4 subtiles of 32 -> uniform phase machinery
#define NOUT 30

typedef _Float16 half8 __attribute__((ext_vector_type(8)));
typedef float f32x4 __attribute__((ext_vector_type(4)));

__device__ __forceinline__ void gload_lds16(const void* g, void* l) {
  __builtin_amdgcn_global_load_lds((const __attribute__((address_space(1))) void*)g,
                                   (__attribute__((address_space(3))) void*)l,
                                   16, 0, 0);
}

__device__ __forceinline__ float sigmoidf_fast(float x) {
  return 1.0f / (1.0f + __expf(-x));
}

// s_waitcnt needs an immediate -> small uniform switch (SGPR branch, ~free)
__device__ __forceinline__ void vmwait(int n) {
  switch (n) {
    case 9:  asm volatile("s_waitcnt vmcnt(9)" ::: "memory"); break;
    case 6:  asm volatile("s_waitcnt vmcnt(6)" ::: "memory"); break;
    case 3:  asm volatile("s_waitcnt vmcnt(3)" ::: "memory"); break;
    default: asm volatile("s_waitcnt vmcnt(0)" ::: "memory"); break;
  }
}

// ---------------------------------------------------------------------------
// Prep kernels (run once per launch; ws is re-poisoned before every call)
// ---------------------------------------------------------------------------

// x [B][T][Fin] fp32 -> xp [T][B][KXP] fp16, zero-padded k in [Fin, KXP)
__global__ __launch_bounds__(256) void convert_x(const float* __restrict__ x,
                                                 _Float16* __restrict__ xp) {
  int idx = blockIdx.x * 256 + threadIdx.x;   // < Tseq*Bsz*KXP
  int k = idx % KXP;
  int b = (idx / KXP) % Bsz;
  int t = idx / (KXP * Bsz);
  float v = (k < Fin) ? x[((size_t)b * Tseq + t) * Fin + k] : 0.0f;
  xp[idx] = (_Float16)v;
}

// W [Fin][G4] fp32 -> Wpt [G4][KXP] fp16 (B^T layout, zero rows k>=Fin)
__global__ __launch_bounds__(256) void transpose_W(const float* __restrict__ W,
                                                   _Float16* __restrict__ Wpt) {
  __shared__ float tile[32][33];
  int n0 = blockIdx.x * 32;
  int k0 = blockIdx.y * 32;
  int tx = threadIdx.x, ty = threadIdx.y;
  for (int i = ty; i < 32; i += 8) {
    int k = k0 + i;
    tile[i][tx] = (k < Fin) ? W[(size_t)k * G4 + n0 + tx] : 0.0f;
  }
  __syncthreads();
  for (int i = ty; i < 32; i += 8)
    Wpt[(size_t)(n0 + i) * KXP + k0 + tx] = (_Float16)tile[tx][i];
}

// U [Hd][G4] fp32 -> Upt [G4][Hd] fp16 (B^T layout)
__global__ __launch_bounds__(256) void transpose_U(const float* __restrict__ U,
                                                   _Float16* __restrict__ Upt) {
  __shared__ float tile[32][33];
  int n0 = blockIdx.x * 32;
  int k0 = blockIdx.y * 32;
  int tx = threadIdx.x, ty = threadIdx.y;
  for (int i = ty; i < 32; i += 8)
    tile[i][tx] = U[(size_t)(k0 + i) * G4 + n0 + tx];
  __syncthreads();
  for (int i = ty; i < 32; i += 8)
    Upt[(size_t)(n0 + i) * Hd + k0 + tx] = (_Float16)tile[tx][i];
}

// ---------------------------------------------------------------------------
// One LSTM step -- m201-style fine-grained phase pipeline.
//
// Round 0-7: every schedule with a MONOLITHIC compute body ([16 reads ->
// wait -> 32 MFMA] per K=64 round) timed at the serial sum of its phases
// (~28.5-31 us/step). This version uses phase granularity (m201: 824 cyc
// per 128-MFMA CU-phase on GEMM):
//
//   K = 1152 = 36 subtiles of 32 (4 of x@W + 32 of h@U).
//   6 half-buffers (A 8KB + B 16KB = 24KB each; 144KB LDS, 1 block/CU).
//   Phase s: { 8 asm ds_read_b128 of half s%6      (issued BEFORE barrier;
//                subtile s landed -- guaranteed by phase s-1's vmcnt+barrier,
//                or by the PROLOGUE wait for s=0 <- round-9 NaN fix)
//              3 global_load_lds staging subtile s+4 into half (s+4)%6
//              s_waitcnt vmcnt(9)   (3 future subtiles in flight; subtile
//                                    s+1 confirmed landed for next phase)
//              s_barrier
//              s_waitcnt lgkmcnt(0) (+sched_barrier, rule #18)
//              setprio(1); 16 MFMA; setprio(0)
//              s_barrier }
//   DMA slack ~3 phases (~2500 cyc) per 24KB subtile (needs ~430 cyc at L2
//   BW) -> off the critical path. WAR: stage at phase s rewrites half
//   (s-2)%6, whose reads finished at phase s-2's lgkmcnt(0), 2+ barriers
//   earlier. All in-flight DMA/read half pairs differ by {1,2,3,4} mod 6.
//
// Tile 128m x 256n (4 gates x 64 units), 8 waves: wave w -> m-half (w>>2),
// j-quarter (w&3); per wave 4mi x 4p fragments; lane holds (i,f,g,o) of one
// hidden unit (m89 layout, shuffle-free epilogue).
//
// LDS unit (16 rows x 32 halfs = 1KB) XOR-chunk swizzle (proven rounds 0-7):
// slot sl of row r holds global chunk sl^((r>>1)&3); staging lane l reads
// global chunk (l&3)^((l>>3)&3); fragment read slot quad^((l16>>1)&3) ->
// perfect permutation, conflict-free (m136), global_load_lds-compatible.
//
// XCD swizzle (256 blocks, 8 XCDs round-robin): XCD x owns j-panels
// 4*(x&3)..+3, m-panels 8*(x>>2)..+7 (bijective, 32 blocks/XCD).
// ---------------------------------------------------------------------------
__global__ __launch_bounds__(512, 1) void lstm_step(
    const _Float16* __restrict__ xp_t,  // [Bsz][KXP]  (this timestep)
    const _Float16* __restrict__ Wpt,   // [G4][KXP]   (B^T)
    const _Float16* __restrict__ Upt,   // [G4][Hd]    (B^T)
    const float*    __restrict__ bias,  // [G4]
    const _Float16* __restrict__ h_in,  // [Bsz][Hd]
    _Float16*       __restrict__ h_out, // [Bsz][Hd]
    float*          __restrict__ cst,   // [Bsz][Hd]
    int skip_h)                          // t==0: only x@W, c_prev = 0
{
  __shared__ __align__(16) _Float16 As[6 * 4096];   // 6 halves x 8 units  = 48KB
  __shared__ __align__(16) _Float16 Bs[6 * 8192];   // 6 halves x 16 units = 96KB

  const int tid  = threadIdx.x;
  const int wave = tid >> 6;          // 0..7
  const int lane = tid & 63;
  const int quad = lane >> 4;
  const int l16  = lane & 15;

  // XCD swizzle: id -> (m-panel, j-panel), 16 x 16 grid, bijective.
  const int id  = blockIdx.x;
  const int xcd = id & 7, loc = id >> 3;              // loc in [0,32)
  const int jpanel = 4 * (xcd & 3) + (loc & 3);       // 0..15
  const int mpanel = 8 * (xcd >> 2) + (loc >> 2);     // 0..15
  const int m0 = mpanel * 128;    // batch-row base
  const int j0 = jpanel * 64;     // hidden-unit base (64 units x 4 gates = 256 N)

  const int srow = lane >> 2;                      // staging row in unit
  const int qg   = (lane & 3) ^ ((lane >> 3) & 3); // staging global chunk
  const int sA   = quad ^ ((l16 >> 1) & 3);        // fragment LDS slot

  const int mhalf = wave >> 2;        // 0..1
  const int nq    = wave & 3;         // 0..3
  const int j  = j0 + 16 * nq + l16;  // this lane's hidden unit
  const int aoff = l16 * 32 + sA * 8; // fragment offset within unit (halfs)

  float bv[4];
#pragma unroll
  for (int p = 0; p < 4; ++p) bv[p] = bias[p * Hd + j];

  f32x4 acc[4][4];
#pragma unroll
  for (int mi = 0; mi < 4; ++mi)
#pragma unroll
    for (int p = 0; p < 4; ++p)
      acc[mi][p] = f32x4{bv[p], bv[p], bv[p], bv[p]};

  const int S = skip_h ? 4 : 36;      // K subtiles of 32

  // stage subtile s (24 KB) into half s%6: exactly 3 gloads per WAVE (1A+2B)
  auto stageSub = [&](int s) {
    const _Float16* Ab; const _Float16* Bb; int strA, strB, k0;
    if (s < 4) { Ab = xp_t; strA = KXP; Bb = Wpt; strB = KXP; k0 = s * 32; }
    else       { Ab = h_in; strA = Hd;  Bb = Upt; strB = Hd;  k0 = (s - 4) * 32; }
    int h = s % 6;
    _Float16* Ad = &As[h * 4096];
    _Float16* Bd = &Bs[h * 8192];
    // A: unit ci = wave (rows m0+ci*16..+15)
    gload_lds16(Ab + (size_t)(m0 + wave * 16 + srow) * strA + k0 + qg * 8,
                Ad + wave * 512);
    // B: units ci = wave, wave+8 (gate ci>>2, j-group ci&3)
#pragma unroll
    for (int ii = 0; ii < 2; ++ii) {
      int ci = ii * 8 + wave;
      int gn = (ci >> 2) * Hd + j0 + 16 * (ci & 3) + srow;
      gload_lds16(Bb + (size_t)gn * strB + k0 + qg * 8, Bd + ci * 512);
    }
  };

  // one phase: reads -> stage -> vmcnt -> barrier -> lgkm(0) -> 16 MFMA -> barrier
  auto phase = [&](int s, int vmN) {
    int h = s % 6;
    const __attribute__((address_space(3))) _Float16* As3 =
        (const __attribute__((address_space(3))) _Float16*)&As[h * 4096];
    const __attribute__((address_space(3))) _Float16* Bs3 =
        (const __attribute__((address_space(3))) _Float16*)&Bs[h * 8192];
    half8 a[4], b[4];
#pragma unroll
    for (int mi = 0; mi < 4; ++mi)
      asm volatile("ds_read_b128 %0, %1" : "=v"(a[mi])
                   : "v"(As3 + (4 * mhalf + mi) * 512 + aoff) : "memory");
#pragma unroll
    for (int p = 0; p < 4; ++p)
      asm volatile("ds_read_b128 %0, %1" : "=v"(b[p])
                   : "v"(Bs3 + (4 * p + nq) * 512 + aoff) : "memory");
    if (s + 4 < S) stageSub(s + 4);
    vmwait(vmN);                        // half for NEXT phase confirmed landed
    __builtin_amdgcn_sched_barrier(0);
    __builtin_amdgcn_s_barrier();
    asm volatile("s_waitcnt lgkmcnt(0)" ::: "memory");
    __builtin_amdgcn_sched_barrier(0);  // rule #18: pin MFMAs below the wait
    __builtin_amdgcn_s_setprio(1);
#pragma unroll
    for (int mi = 0; mi < 4; ++mi)
#pragma unroll
      for (int p = 0; p < 4; ++p)
        acc[mi][p] = __builtin_amdgcn_mfma_f32_16x16x32_f16(a[mi], b[p],
                                                            acc[mi][p], 0, 0, 0);
    __builtin_amdgcn_s_setprio(0);
    __builtin_amdgcn_s_barrier();
  };

  // prologue: fill 4 subtiles (12 gloads/wave in flight)
  stageSub(0);
  stageSub(1);
  stageSub(2);
  stageSub(3);
  // ROUND-9 FIX: establish the steady-state precondition before phase 0.
  // vmcnt(9) -> subtile 0 landed (1..3 still in flight); barrier -> ALL
  // waves' subtile-0 loads landed before any wave's phase-0 ds_reads.
  // (Without this, phase 0 read uninitialized LDS -> NaN through the acc.)
  vmwait(9);
  __builtin_amdgcn_sched_barrier(0);
  __builtin_amdgcn_s_barrier();

  // main: steady-state vmcnt(9) = 3 future subtiles in flight
  int s = 0;
  for (; s < S - 4; ++s) phase(s, 9);
  // tail: drain (vmN = 3 * clamp(S-2-s, 0, 3))
  for (; s < S; ++s) {
    int rem = S - 2 - s;
    phase(s, rem >= 3 ? 9 : (rem > 0 ? 3 * rem : 0));
  }

  // epilogue: lane holds i,f,g,o for hidden unit j, rows quad*4+rr (m89 layout)
#pragma unroll
  for (int mi = 0; mi < 4; ++mi) {
#pragma unroll
    for (int rr = 0; rr < 4; ++rr) {
      int row = m0 + 64 * mhalf + mi * 16 + quad * 4 + rr;
      size_t idx = (size_t)row * Hd + j;
      float iv = sigmoidf_fast(acc[mi][0][rr]);
      float fv = sigmoidf_fast(acc[mi][1][rr]);
      float gv = fmaxf(acc[mi][2][rr], 0.0f);   // relu candidate
      float ov = sigmoidf_fast(acc[mi][3][rr]);
      float cprev = skip_h ? 0.0f : cst[idx];   // c_0 = 0 folded in
      float cv = fv * cprev + iv * gv;
      cst[idx] = cv;
      float hv = ov * fmaxf(cv, 0.0f);          // relu on cell output
      h_out[idx] = (_Float16)hv;
    }
  }
}

// ---------------------------------------------------------------------------
// y[b][o] = bd[o] + sum_k h[b][k] * Wd[k][o]
// ---------------------------------------------------------------------------
__global__ __launch_bounds__(256) void final_dense(const _Float16* __restrict__ h,
                                                   const float* __restrict__ Wd,
                                                   const float* __restrict__ bd,
                                                   float* __restrict__ y) {
  __shared__ float hs[Hd];
  __shared__ float red[8][32];
  int bi = blockIdx.x;
  for (int k = threadIdx.x; k < Hd; k += 256)
    hs[k] = (float)h[(size_t)bi * Hd + k];
  __syncthreads();
  int o  = threadIdx.x & 31;
  int ch = threadIdx.x >> 5;
  float p = 0.0f;
  if (o < NOUT) {
    int k0 = ch * (Hd / 8);
    for (int k = k0; k < k0 + (Hd / 8); ++k)
      p += hs[k] * Wd[(size_t)k * NOUT + o];
  }
  red[ch][o] = p;
  __syncthreads();
  if (threadIdx.x < NOUT) {
    float s = bd[threadIdx.x];
    for (int c2 = 0; c2 < 8; ++c2) s += red[c2][threadIdx.x];
    y[(size_t)bi * NOUT + threadIdx.x] = s;
  }
}

// ---------------------------------------------------------------------------

extern "C" void kernel_launch(void* const* d_in, const int* in_sizes, int n_in,
                              void* d_out, int out_size, void* d_ws, size_t ws_size,
                              hipStream_t stream) {
  const float* x  = (const float*)d_in[0];
  const float* W  = (const float*)d_in[1];
  const float* U  = (const float*)d_in[2];
  const float* b  = (const float*)d_in[3];
  const float* Wd = (const float*)d_in[4];
  const float* bd = (const float*)d_in[5];
  float* y = (float*)d_out;

  char* ws = (char*)d_ws;
  _Float16* xp  = (_Float16*)ws; ws += (size_t)Tseq * Bsz * KXP * 2;  // 31.5 MB
  _Float16* Wpt = (_Float16*)ws; ws += (size_t)G4 * KXP * 2;          // 1.05 MB
  _Float16* Upt = (_Float16*)ws; ws += (size_t)G4 * Hd * 2;           // 8.4 MB
  _Float16* hb0 = (_Float16*)ws; ws += (size_t)Bsz * Hd * 2;          // 4.2 MB
  _Float16* hb1 = (_Float16*)ws; ws += (size_t)Bsz * Hd * 2;          // 4.2 MB
  float*    cst = (float*)ws;    ws += (size_t)Bsz * Hd * 4;          // 8.4 MB

  convert_x<<<(Tseq * Bsz * KXP) / 256, 256, 0, stream>>>(x, xp);
  transpose_W<<<dim3(G4 / 32, KXP / 32), dim3(32, 8), 0, stream>>>(W, Wpt);
  transpose_U<<<dim3(G4 / 32, Hd / 32), dim3(32, 8), 0, stream>>>(U, Upt);

  for (int t = 0; t < Tseq; ++t) {
    const _Float16* hin  = ((t - 1) & 1) ? hb1 : hb0;   // unused at t=0
    _Float16*       hout = (t & 1) ? hb1 : hb0;
    lstm_step<<<dim3((Bsz / 128) * (G4 / 256)), 512, 0, stream>>>(
        xp + (size_t)t * (Bsz * KXP), Wpt, Upt, b,
        (t == 0) ? hb0 : hin, hout, cst, (t == 0) ? 1 : 0);
  }

  // h_{59} is in hb1 (59 & 1 == 1)
  final_dense<<<Bsz, 256, 0, stream>>>(hb1, Wd, bd, y);
}